// Round 4
// baseline (1132.430 us; speedup 1.0000x reference)
//
#include <hip/hip_runtime.h>

constexpr float NEG_SLOPE = 0.2f;
constexpr float EPS = 1e-16f;
constexpr float NEG_INF = -1e30f;

// ================= CSR build (with one self-loop slot appended per node) ====
// slots of node v: [rowptr[v], rowptr[v+1]); the LAST slot is the self-loop.

__global__ void count_k(const int* __restrict__ dst, int* __restrict__ cnt, int E) {
    int i = blockIdx.x * blockDim.x + threadIdx.x;
    if (i < E) atomicAdd(&cnt[dst[i]], 1);
}

// exclusive scan of (cnt[i] + 1)  — the +1 is the self-loop slot
__global__ void scan1_k(const int* __restrict__ in, int* __restrict__ out,
                        int* __restrict__ bsum, int n) {
    __shared__ int s[256];
    int tid = threadIdx.x;
    int i = blockIdx.x * 256 + tid;
    int v = (i < n) ? in[i] + 1 : 0;
    s[tid] = v;
    __syncthreads();
    #pragma unroll
    for (int off = 1; off < 256; off <<= 1) {
        int t = (tid >= off) ? s[tid - off] : 0;
        __syncthreads();
        s[tid] += t;
        __syncthreads();
    }
    if (i < n) out[i] = s[tid] - v;
    if (tid == 255) bsum[blockIdx.x] = s[255];
}

__global__ void scan2_k(int* __restrict__ bsum, int nb) {
    __shared__ int s[1024];
    int tid = threadIdx.x;
    int v = (tid < nb) ? bsum[tid] : 0;
    s[tid] = v;
    __syncthreads();
    #pragma unroll
    for (int off = 1; off < 1024; off <<= 1) {
        int t = (tid >= off) ? s[tid - off] : 0;
        __syncthreads();
        s[tid] += t;
        __syncthreads();
    }
    if (tid < nb) bsum[tid] = s[tid] - v;
}

__global__ void scan3_k(int* __restrict__ rowptr, const int* __restrict__ bsum,
                        int n, int M) {
    int i = blockIdx.x * 256 + threadIdx.x;
    if (i < n) rowptr[i] += bsum[blockIdx.x];
    if (i == 0) rowptr[n] = M;
}

__global__ void fill_k(const int* __restrict__ src, const int* __restrict__ dst,
                       const int* __restrict__ rowptr, int* __restrict__ fill,
                       int* __restrict__ ssrc, int* __restrict__ sdst,
                       int* __restrict__ seid, int E) {
    int i = blockIdx.x * blockDim.x + threadIdx.x;
    if (i < E) {
        int d = dst[i];
        int pos = rowptr[d] + atomicAdd(&fill[d], 1);
        ssrc[pos] = src[i];
        sdst[pos] = d;
        seid[pos] = i;        // seid sized M; self slots stay -1 (memset 0xFF)
    }
}

// permute edge_attr into CSR slot order; self slots (seid<0) are skipped
// (mean_k fills them with the per-node mean row).
__global__ void permute_k(const float* __restrict__ ea, const int* __restrict__ seid,
                          float* __restrict__ eperm, int M) {
    int t = blockIdx.x * blockDim.x + threadIdx.x;   // t = k*4 + c
    if (t >= M * 4) return;
    int k = t >> 2, c = t & 3;
    int eid = seid[k];
    if (eid < 0) return;      // self-loop slot
    const float4* srcr = reinterpret_cast<const float4*>(ea) + (size_t)eid * 4;
    reinterpret_cast<float4*>(eperm)[(size_t)k * 4 + c] = srcr[c];
}

// mean incoming edge_attr; PERM=1 writes the mean directly into the self-loop
// row of eperm; PERM=0 writes mattr. Also fills ssrc/sdst for the self slot.
template <int PERM>
__global__ void mean_k(const float* __restrict__ ea, const int* __restrict__ seid,
                       const int* __restrict__ rowptr,
                       float* __restrict__ eperm, float* __restrict__ mattr,
                       int* __restrict__ ssrc, int* __restrict__ sdst, int N) {
    int t = blockIdx.x * blockDim.x + threadIdx.x;
    if (t >= N * 16) return;
    int v = t >> 4, f = t & 15;
    int s = rowptr[v], sEnd = rowptr[v + 1] - 1;   // real edges in [s, sEnd)
    float sum = 0.f;
    for (int k = s; k < sEnd; k++) {
        size_t row = PERM ? (size_t)k : (size_t)seid[k];
        sum += PERM ? eperm[row * 16 + f] : ea[row * 16 + f];
    }
    int c = sEnd - s;
    float mean = sum / (float)(c > 1 ? c : 1);
    if (PERM) eperm[(size_t)sEnd * 16 + f] = mean;
    else      mattr[(size_t)v * 16 + f] = mean;
    if (f == 0) { ssrc[sEnd] = v; sdst[sEnd] = v; }
}

// ============= node transforms: xl = x@Wl+bl, xr = x@Wr+br ==================

__global__ __launch_bounds__(256) void xfrm_k(
        const float* __restrict__ x,
        const float* __restrict__ Wl, const float* __restrict__ bl,
        const float* __restrict__ Wr, const float* __restrict__ br,
        float* __restrict__ xl, float* __restrict__ xr, int N) {
    __shared__ float sWl[64 * 64];
    __shared__ float sWr[64 * 64];
    for (int i = threadIdx.x; i < 64 * 64; i += 256) {
        sWl[i] = Wl[i];
        sWr[i] = Wr[i];
    }
    __syncthreads();
    int v = blockIdx.x * 4 + (threadIdx.x >> 6);
    int h = threadIdx.x & 63;
    if (v >= N) return;
    const float4* xrow = reinterpret_cast<const float4*>(x + (size_t)v * 64);
    float al = bl[h], ar = br[h];
    #pragma unroll
    for (int d4 = 0; d4 < 16; d4++) {
        float4 xv = xrow[d4];
        int d = d4 * 4;
        al = fmaf(xv.x, sWl[(d + 0) * 64 + h], al);
        al = fmaf(xv.y, sWl[(d + 1) * 64 + h], al);
        al = fmaf(xv.z, sWl[(d + 2) * 64 + h], al);
        al = fmaf(xv.w, sWl[(d + 3) * 64 + h], al);
        ar = fmaf(xv.x, sWr[(d + 0) * 64 + h], ar);
        ar = fmaf(xv.y, sWr[(d + 1) * 64 + h], ar);
        ar = fmaf(xv.z, sWr[(d + 2) * 64 + h], ar);
        ar = fmaf(xv.w, sWr[(d + 3) * 64 + h], ar);
    }
    xl[(size_t)v * 64 + h] = al;
    xr[(size_t)v * 64 + h] = ar;
}

// ================= Pass A: per-slot attention scores ========================
// one wave per 4 CSR slots; lane = feature; fully parallel, no serial chain.

__device__ __forceinline__ float dot16(const float4* __restrict__ q,
                                       const float* __restrict__ wec) {
    float4 q0 = q[0], q1 = q[1], q2 = q[2], q3 = q[3];
    float ee = q0.x * wec[0];
    ee = fmaf(q0.y, wec[1], ee);
    ee = fmaf(q0.z, wec[2], ee);
    ee = fmaf(q0.w, wec[3], ee);
    ee = fmaf(q1.x, wec[4], ee);
    ee = fmaf(q1.y, wec[5], ee);
    ee = fmaf(q1.z, wec[6], ee);
    ee = fmaf(q1.w, wec[7], ee);
    ee = fmaf(q2.x, wec[8], ee);
    ee = fmaf(q2.y, wec[9], ee);
    ee = fmaf(q2.z, wec[10], ee);
    ee = fmaf(q2.w, wec[11], ee);
    ee = fmaf(q3.x, wec[12], ee);
    ee = fmaf(q3.y, wec[13], ee);
    ee = fmaf(q3.z, wec[14], ee);
    ee = fmaf(q3.w, wec[15], ee);
    return ee;
}

template <int PERM>
__global__ __launch_bounds__(256) void escore_k(
        const float* __restrict__ xl, const float* __restrict__ xr,
        const float* __restrict__ ea,      // eperm (PERM=1) or raw edge_attr
        const int* __restrict__ seid, const float* __restrict__ mattr,
        const int* __restrict__ ssrc, const int* __restrict__ sdst,
        const int* __restrict__ rowptr,
        const float* __restrict__ We, const float* __restrict__ att,
        float* __restrict__ escr, int M) {
    int lane = threadIdx.x & 63;
    int wid = blockIdx.x * 4 + (threadIdx.x >> 6);
    int base = wid * 4;
    if (base >= M) return;

    float wec[16];
    #pragma unroll
    for (int d = 0; d < 16; d++) wec[d] = We[d * 64 + lane];
    float att_h = att[lane];

    float p[4];
    #pragma unroll
    for (int i = 0; i < 4; i++) {
        int k = base + i;
        int kk = (k < M) ? k : (M - 1);      // clamp; guarded on write
        int srcn = ssrc[kk];
        int dstn = sdst[kk];
        const float4* q;
        if (PERM) {
            q = reinterpret_cast<const float4*>(ea) + (size_t)kk * 4;
        } else {
            int eid = seid[kk];
            q = (eid < 0) ? reinterpret_cast<const float4*>(mattr) + (size_t)dstn * 4
                          : reinterpret_cast<const float4*>(ea) + (size_t)eid * 4;
        }
        float ee = dot16(q, wec);
        float xls = xl[(size_t)srcn * 64 + lane];
        float xrs = xr[(size_t)dstn * 64 + lane];
        float mv = xls + xrs + ee;
        mv = (mv > 0.f) ? mv : NEG_SLOPE * mv;
        p[i] = att_h * mv;
    }
    #pragma unroll
    for (int off = 32; off; off >>= 1) {
        p[0] += __shfl_xor(p[0], off);
        p[1] += __shfl_xor(p[1], off);
        p[2] += __shfl_xor(p[2], off);
        p[3] += __shfl_xor(p[3], off);
    }
    float pv = (lane == 0) ? p[0] : (lane == 1) ? p[1] : (lane == 2) ? p[2] : p[3];
    if (lane < 4 && base + lane < M) escr[base + lane] = pv;
}

// ================= Pass B: softmax + weighted aggregation ===================
// one wave per node. Scores are contiguous -> butterflies per NODE, not edge.
// MODE 0: write h = relu(out). MODE 1: fuse relu + JK-cat readout.

template <int MODE>
__global__ __launch_bounds__(256) void aggregate_k(
        const float* __restrict__ xl, const float* __restrict__ escr,
        const int* __restrict__ ssrc, const int* __restrict__ rowptr,
        const float* __restrict__ bc,
        float* __restrict__ hout,
        const float* __restrict__ h1, const float* __restrict__ Wout,
        const float* __restrict__ bout, float* __restrict__ out, int N) {
    int lane = threadIdx.x & 63;
    int v = blockIdx.x * 4 + (threadIdx.x >> 6);
    if (v >= N) return;

    int s = rowptr[v], e = rowptr[v + 1];   // includes self slot; e > s always

    // wave max over all slots
    float m = NEG_INF;
    for (int b = s; b < e; b += 64) {
        int idx = b + lane;
        float val = (idx < e) ? escr[idx] : NEG_INF;
        #pragma unroll
        for (int off = 32; off; off >>= 1) val = fmaxf(val, __shfl_xor(val, off));
        m = fmaxf(m, val);
    }
    // denominator
    float denom = 0.f;
    for (int b = s; b < e; b += 64) {
        int idx = b + lane;
        float t = (idx < e) ? __expf(escr[idx] - m) : 0.f;
        #pragma unroll
        for (int off = 32; off; off >>= 1) t += __shfl_xor(t, off);
        denom += t;
    }
    float inv = 1.f / (denom + EPS);

    // weighted aggregation: only dependency through acc (one FMA per edge)
    float acc = 0.f;
    for (int b = s; b < e; b += 64) {
        int idx = b + lane;
        float wv = (idx < e) ? __expf(escr[idx] - m) * inv : 0.f;
        int nj = min(64, e - b);
        #pragma unroll 4
        for (int j = 0; j < nj; j++) {
            float wk = __shfl(wv, j);
            int srcn = ssrc[b + j];
            acc = fmaf(wk, xl[(size_t)srcn * 64 + lane], acc);
        }
    }

    float res = fmaxf(acc + bc[lane], 0.f);

    if (MODE == 0) {
        hout[(size_t)v * 64 + lane] = res;
    } else {
        float part = h1[(size_t)v * 64 + lane] * Wout[lane] + res * Wout[64 + lane];
        #pragma unroll
        for (int off = 32; off; off >>= 1) part += __shfl_xor(part, off);
        if (lane == 0) out[v] = part + bout[0];
    }
}

// ================= launch ===================================================

extern "C" void kernel_launch(void* const* d_in, const int* in_sizes, int n_in,
                              void* d_out, int out_size, void* d_ws, size_t ws_size,
                              hipStream_t stream) {
    const float* x     = (const float*)d_in[0];
    const int*   eidx  = (const int*)d_in[1];
    const float* eattr = (const float*)d_in[2];
    const float* Wl1 = (const float*)d_in[4];
    const float* bl1 = (const float*)d_in[5];
    const float* Wr1 = (const float*)d_in[6];
    const float* br1 = (const float*)d_in[7];
    const float* We1 = (const float*)d_in[8];
    const float* att1 = (const float*)d_in[9];
    const float* bc1 = (const float*)d_in[10];
    const float* Wl2 = (const float*)d_in[11];
    const float* bl2 = (const float*)d_in[12];
    const float* Wr2 = (const float*)d_in[13];
    const float* br2 = (const float*)d_in[14];
    const float* We2 = (const float*)d_in[15];
    const float* att2 = (const float*)d_in[16];
    const float* bc2 = (const float*)d_in[17];
    const float* Wout = (const float*)d_in[18];
    const float* bout = (const float*)d_in[19];

    int N = in_sizes[0] / 64;
    int E = in_sizes[1] / 2;
    int M = E + N;                       // CSR slots incl. self-loops
    const int* srcA = eidx;
    const int* dstA = eidx + E;

    char* w = (char*)d_ws;
    size_t used = 0;
    auto alloc = [&](size_t bytes) {
        char* p = w + used;
        used += (bytes + 255) & ~size_t(255);
        return p;
    };
    int*   cnt    = (int*)alloc((size_t)N * 4);
    int*   fill   = (int*)alloc((size_t)N * 4);
    int*   rowptr = (int*)alloc((size_t)(N + 1) * 4);
    int*   bsum   = (int*)alloc(1024 * 4);
    int*   ssrc   = (int*)alloc((size_t)M * 4);
    int*   sdst   = (int*)alloc((size_t)M * 4);
    int*   seid   = (int*)alloc((size_t)M * 4);   // -1 marks self-loop slots
    float* escr   = (float*)alloc((size_t)M * 4);
    float* mattr  = (float*)alloc((size_t)N * 16 * 4);
    float* xl     = (float*)alloc((size_t)N * 64 * 4);
    float* xr     = (float*)alloc((size_t)N * 64 * 4);
    float* h1     = (float*)alloc((size_t)N * 64 * 4);
    size_t eperm_bytes = (size_t)M * 16 * 4;
    bool perm = (used + eperm_bytes) <= ws_size;
    float* eperm = perm ? (float*)alloc(eperm_bytes) : nullptr;

    hipMemsetAsync(cnt, 0, (size_t)N * 4, stream);
    hipMemsetAsync(fill, 0, (size_t)N * 4, stream);
    hipMemsetAsync(seid, 0xFF, (size_t)M * 4, stream);   // all -1

    int NB = (N + 255) / 256;
    count_k<<<(E + 255) / 256, 256, 0, stream>>>(dstA, cnt, E);
    scan1_k<<<NB, 256, 0, stream>>>(cnt, rowptr, bsum, N);
    scan2_k<<<1, 1024, 0, stream>>>(bsum, NB);
    scan3_k<<<NB, 256, 0, stream>>>(rowptr, bsum, N, M);
    fill_k<<<(E + 255) / 256, 256, 0, stream>>>(srcA, dstA, rowptr, fill,
                                                ssrc, sdst, seid, E);

    const float* eaN = eattr;
    if (perm) {
        permute_k<<<(M * 4 + 255) / 256, 256, 0, stream>>>(eattr, seid, eperm, M);
        eaN = eperm;
        mean_k<1><<<(N * 16 + 255) / 256, 256, 0, stream>>>(
            eattr, seid, rowptr, eperm, mattr, ssrc, sdst, N);
    } else {
        mean_k<0><<<(N * 16 + 255) / 256, 256, 0, stream>>>(
            eattr, seid, rowptr, nullptr, mattr, ssrc, sdst, N);
    }

    int nodeBlocks = (N + 3) / 4;
    int slotBlocks = (M + 15) / 16;

    // ---- layer 1
    xfrm_k<<<nodeBlocks, 256, 0, stream>>>(x, Wl1, bl1, Wr1, br1, xl, xr, N);
    if (perm)
        escore_k<1><<<slotBlocks, 256, 0, stream>>>(xl, xr, eaN, seid, mattr, ssrc,
                                                    sdst, rowptr, We1, att1, escr, M);
    else
        escore_k<0><<<slotBlocks, 256, 0, stream>>>(xl, xr, eaN, seid, mattr, ssrc,
                                                    sdst, rowptr, We1, att1, escr, M);
    aggregate_k<0><<<nodeBlocks, 256, 0, stream>>>(xl, escr, ssrc, rowptr, bc1, h1,
                                                   nullptr, nullptr, nullptr, nullptr, N);

    // ---- layer 2 (+ fused JK-cat readout)
    xfrm_k<<<nodeBlocks, 256, 0, stream>>>(h1, Wl2, bl2, Wr2, br2, xl, xr, N);
    if (perm)
        escore_k<1><<<slotBlocks, 256, 0, stream>>>(xl, xr, eaN, seid, mattr, ssrc,
                                                    sdst, rowptr, We2, att2, escr, M);
    else
        escore_k<0><<<slotBlocks, 256, 0, stream>>>(xl, xr, eaN, seid, mattr, ssrc,
                                                    sdst, rowptr, We2, att2, escr, M);
    aggregate_k<1><<<nodeBlocks, 256, 0, stream>>>(xl, escr, ssrc, rowptr, bc2, nullptr,
                                                   h1, Wout, bout, (float*)d_out, N);
}

// Round 5
// 701.847 us; speedup vs baseline: 1.6135x; 1.6135x over previous
//
#include <hip/hip_runtime.h>

constexpr float NEG_SLOPE = 0.2f;
constexpr float EPS = 1e-16f;
constexpr float NEG_INF = -1e30f;

// ================= CSR build (self-loop slot = LAST slot of each node) ======

__global__ void count_k(const int* __restrict__ dst, int* __restrict__ cnt, int E) {
    int i = blockIdx.x * blockDim.x + threadIdx.x;
    if (i < E) atomicAdd(&cnt[dst[i]], 1);
}

__global__ void scan1_k(const int* __restrict__ in, int* __restrict__ out,
                        int* __restrict__ bsum, int n) {
    __shared__ int s[256];
    int tid = threadIdx.x;
    int i = blockIdx.x * 256 + tid;
    int v = (i < n) ? in[i] + 1 : 0;   // +1 self-loop slot
    s[tid] = v;
    __syncthreads();
    #pragma unroll
    for (int off = 1; off < 256; off <<= 1) {
        int t = (tid >= off) ? s[tid - off] : 0;
        __syncthreads();
        s[tid] += t;
        __syncthreads();
    }
    if (i < n) out[i] = s[tid] - v;
    if (tid == 255) bsum[blockIdx.x] = s[255];
}

__global__ void scan2_k(int* __restrict__ bsum, int nb) {
    __shared__ int s[1024];
    int tid = threadIdx.x;
    int v = (tid < nb) ? bsum[tid] : 0;
    s[tid] = v;
    __syncthreads();
    #pragma unroll
    for (int off = 1; off < 1024; off <<= 1) {
        int t = (tid >= off) ? s[tid - off] : 0;
        __syncthreads();
        s[tid] += t;
        __syncthreads();
    }
    if (tid < nb) bsum[tid] = s[tid] - v;
}

__global__ void scan3_k(int* __restrict__ rowptr, const int* __restrict__ bsum,
                        int n, int M) {
    int i = blockIdx.x * 256 + threadIdx.x;
    if (i < n) rowptr[i] += bsum[blockIdx.x];
    if (i == 0) rowptr[n] = M;
}

__global__ void fill_k(const int* __restrict__ src, const int* __restrict__ dst,
                       const int* __restrict__ rowptr, int* __restrict__ fill,
                       int* __restrict__ ssrc, int* __restrict__ sdst,
                       int* __restrict__ seid, int E) {
    int i = blockIdx.x * blockDim.x + threadIdx.x;
    if (i < E) {
        int d = dst[i];
        int pos = rowptr[d] + atomicAdd(&fill[d], 1);
        ssrc[pos] = src[i];
        sdst[pos] = d;
        seid[pos] = i;        // self slots stay -1 (memset 0xFF)
    }
}

// permute edge_attr into CSR slot order; self slots (seid<0) skipped here,
// filled by mean_k.
__global__ void permute_k(const float* __restrict__ ea, const int* __restrict__ seid,
                          float* __restrict__ eperm, int M) {
    int t = blockIdx.x * blockDim.x + threadIdx.x;   // t = k*4 + c
    if (t >= M * 4) return;
    int k = t >> 2, c = t & 3;
    int eid = seid[k];
    if (eid < 0) return;
    const float4* srcr = reinterpret_cast<const float4*>(ea) + (size_t)eid * 4;
    reinterpret_cast<float4*>(eperm)[(size_t)k * 4 + c] = srcr[c];
}

template <int PERM>
__global__ void mean_k(const float* __restrict__ ea, const int* __restrict__ seid,
                       const int* __restrict__ rowptr,
                       float* __restrict__ eperm, float* __restrict__ mattr,
                       int* __restrict__ ssrc, int* __restrict__ sdst, int N) {
    int t = blockIdx.x * blockDim.x + threadIdx.x;
    if (t >= N * 16) return;
    int v = t >> 4, f = t & 15;
    int s = rowptr[v], sEnd = rowptr[v + 1] - 1;   // real edges in [s, sEnd)
    float sum = 0.f;
    for (int k = s; k < sEnd; k++) {
        size_t row = PERM ? (size_t)k : (size_t)seid[k];
        sum += PERM ? eperm[row * 16 + f] : ea[row * 16 + f];
    }
    int c = sEnd - s;
    float mean = sum / (float)(c > 1 ? c : 1);
    if (PERM) eperm[(size_t)sEnd * 16 + f] = mean;
    else      mattr[(size_t)v * 16 + f] = mean;
    if (f == 0) { ssrc[sEnd] = v; sdst[sEnd] = v; }
}

// ============= node transforms: xl = x@Wl+bl, xr = x@Wr+br ==================

__global__ __launch_bounds__(256) void xfrm_k(
        const float* __restrict__ x,
        const float* __restrict__ Wl, const float* __restrict__ bl,
        const float* __restrict__ Wr, const float* __restrict__ br,
        float* __restrict__ xl, float* __restrict__ xr, int N) {
    __shared__ float sWl[64 * 64];
    __shared__ float sWr[64 * 64];
    for (int i = threadIdx.x; i < 64 * 64; i += 256) {
        sWl[i] = Wl[i];
        sWr[i] = Wr[i];
    }
    __syncthreads();
    int v = blockIdx.x * 4 + (threadIdx.x >> 6);
    int h = threadIdx.x & 63;
    if (v >= N) return;
    const float4* xrow = reinterpret_cast<const float4*>(x + (size_t)v * 64);
    float al = bl[h], ar = br[h];
    #pragma unroll
    for (int d4 = 0; d4 < 16; d4++) {
        float4 xv = xrow[d4];
        int d = d4 * 4;
        al = fmaf(xv.x, sWl[(d + 0) * 64 + h], al);
        al = fmaf(xv.y, sWl[(d + 1) * 64 + h], al);
        al = fmaf(xv.z, sWl[(d + 2) * 64 + h], al);
        al = fmaf(xv.w, sWl[(d + 3) * 64 + h], al);
        ar = fmaf(xv.x, sWr[(d + 0) * 64 + h], ar);
        ar = fmaf(xv.y, sWr[(d + 1) * 64 + h], ar);
        ar = fmaf(xv.z, sWr[(d + 2) * 64 + h], ar);
        ar = fmaf(xv.w, sWr[(d + 3) * 64 + h], ar);
    }
    xl[(size_t)v * 64 + h] = al;
    xr[(size_t)v * 64 + h] = ar;
}

// ================= Pass A: per-slot scores, LANE = EDGE =====================
// Each lane owns 2 slots; reduction over the 64 features happens in a scalar
// register accumulator — no cross-lane ops at all. We/att broadcast from LDS.

template <int PERM>
__global__ __launch_bounds__(256) void escore_k(
        const float* __restrict__ xl, const float* __restrict__ xr,
        const float* __restrict__ eperm,   // CSR-ordered attrs (PERM=1)
        const float* __restrict__ earaw, const int* __restrict__ seid,
        const float* __restrict__ mattr,
        const int* __restrict__ ssrc, const int* __restrict__ sdst,
        const float* __restrict__ We, const float* __restrict__ att,
        float* __restrict__ escr, int M) {
    __shared__ float4 sWe[16 * 16];   // [d][j] = We[d][4j..4j+3]
    __shared__ float4 sAtt[16];
    int tid = threadIdx.x;
    {
        const float4* We4 = reinterpret_cast<const float4*>(We);
        if (tid < 256) sWe[tid] = We4[tid];
        if (tid < 16) sAtt[tid] = reinterpret_cast<const float4*>(att)[tid];
    }
    __syncthreads();

    int lane = tid & 63;
    int base = (blockIdx.x * 4 + (tid >> 6)) * 128;
    if (base >= M) return;
    int k0 = base + lane;
    int k1 = k0 + 64;
    int k0c = min(k0, M - 1);
    int k1c = min(k1, M - 1);

    int s0 = ssrc[k0c], d0 = sdst[k0c];
    int s1 = ssrc[k1c], d1 = sdst[k1c];

    const float4* rp0;
    const float4* rp1;
    if (PERM) {
        rp0 = reinterpret_cast<const float4*>(eperm) + (size_t)k0c * 4;
        rp1 = reinterpret_cast<const float4*>(eperm) + (size_t)k1c * 4;
    } else {
        int e0 = seid[k0c], e1 = seid[k1c];
        rp0 = (e0 < 0) ? reinterpret_cast<const float4*>(mattr) + (size_t)d0 * 4
                       : reinterpret_cast<const float4*>(earaw) + (size_t)e0 * 4;
        rp1 = (e1 < 0) ? reinterpret_cast<const float4*>(mattr) + (size_t)d1 * 4
                       : reinterpret_cast<const float4*>(earaw) + (size_t)e1 * 4;
    }

    float ea0[16], ea1[16];
    #pragma unroll
    for (int q = 0; q < 4; q++) {
        float4 a = rp0[q];
        ea0[q * 4 + 0] = a.x; ea0[q * 4 + 1] = a.y;
        ea0[q * 4 + 2] = a.z; ea0[q * 4 + 3] = a.w;
        float4 b = rp1[q];
        ea1[q * 4 + 0] = b.x; ea1[q * 4 + 1] = b.y;
        ea1[q * 4 + 2] = b.z; ea1[q * 4 + 3] = b.w;
    }

    const float4* xl4 = reinterpret_cast<const float4*>(xl);
    const float4* xr4 = reinterpret_cast<const float4*>(xr);
    size_t xs0 = (size_t)s0 * 16, xd0 = (size_t)d0 * 16;
    size_t xs1 = (size_t)s1 * 16, xd1 = (size_t)d1 * 16;

    float acc0 = 0.f, acc1 = 0.f;
    #pragma unroll 4
    for (int j = 0; j < 16; ++j) {
        float4 x0 = xl4[xs0 + j];
        float4 r0 = xr4[xd0 + j];
        float4 x1 = xl4[xs1 + j];
        float4 r1 = xr4[xd1 + j];
        float4 ee0 = {0.f, 0.f, 0.f, 0.f};
        float4 ee1 = {0.f, 0.f, 0.f, 0.f};
        #pragma unroll
        for (int d = 0; d < 16; ++d) {
            float4 w = sWe[d * 16 + j];
            float a0 = ea0[d], a1 = ea1[d];
            ee0.x = fmaf(a0, w.x, ee0.x);
            ee0.y = fmaf(a0, w.y, ee0.y);
            ee0.z = fmaf(a0, w.z, ee0.z);
            ee0.w = fmaf(a0, w.w, ee0.w);
            ee1.x = fmaf(a1, w.x, ee1.x);
            ee1.y = fmaf(a1, w.y, ee1.y);
            ee1.z = fmaf(a1, w.z, ee1.z);
            ee1.w = fmaf(a1, w.w, ee1.w);
        }
        float4 a4 = sAtt[j];
        float m;
        m = x0.x + r0.x + ee0.x; m = (m > 0.f) ? m : NEG_SLOPE * m; acc0 = fmaf(a4.x, m, acc0);
        m = x0.y + r0.y + ee0.y; m = (m > 0.f) ? m : NEG_SLOPE * m; acc0 = fmaf(a4.y, m, acc0);
        m = x0.z + r0.z + ee0.z; m = (m > 0.f) ? m : NEG_SLOPE * m; acc0 = fmaf(a4.z, m, acc0);
        m = x0.w + r0.w + ee0.w; m = (m > 0.f) ? m : NEG_SLOPE * m; acc0 = fmaf(a4.w, m, acc0);
        m = x1.x + r1.x + ee1.x; m = (m > 0.f) ? m : NEG_SLOPE * m; acc1 = fmaf(a4.x, m, acc1);
        m = x1.y + r1.y + ee1.y; m = (m > 0.f) ? m : NEG_SLOPE * m; acc1 = fmaf(a4.y, m, acc1);
        m = x1.z + r1.z + ee1.z; m = (m > 0.f) ? m : NEG_SLOPE * m; acc1 = fmaf(a4.z, m, acc1);
        m = x1.w + r1.w + ee1.w; m = (m > 0.f) ? m : NEG_SLOPE * m; acc1 = fmaf(a4.w, m, acc1);
    }
    if (k0 < M) escr[k0] = acc0;
    if (k1 < M) escr[k1] = acc1;
}

// ================= Pass B: softmax + weighted aggregation ===================

__device__ __forceinline__ float rdlanef(float x, int j) {
    return __int_as_float(__builtin_amdgcn_readlane(__float_as_int(x), j));
}

template <int MODE>
__global__ __launch_bounds__(256) void aggregate_k(
        const float* __restrict__ xl, const float* __restrict__ escr,
        const int* __restrict__ ssrc, const int* __restrict__ rowptr,
        const float* __restrict__ bc,
        float* __restrict__ hout,
        const float* __restrict__ h1, const float* __restrict__ Wout,
        const float* __restrict__ bout, float* __restrict__ out, int N) {
    int lane = threadIdx.x & 63;
    int v = blockIdx.x * 4 + (threadIdx.x >> 6);
    if (v >= N) return;

    int s = rowptr[v], e = rowptr[v + 1];
    int deg = e - s;
    float acc;

    if (deg <= 64) {
        // ---- fast path: all scores fit one wave
        int idx = s + lane;
        bool valid = lane < deg;
        float sc = valid ? escr[idx] : NEG_INF;
        float m = sc;
        #pragma unroll
        for (int off = 32; off; off >>= 1) m = fmaxf(m, __shfl_xor(m, off));
        float t = valid ? __expf(sc - m) : 0.f;
        float dsum = t;
        #pragma unroll
        for (int off = 32; off; off >>= 1) dsum += __shfl_xor(dsum, off);
        float alpha = t / (dsum + EPS);
        int srcn = valid ? ssrc[idx] : 0;

        float a0 = 0.f, a1 = 0.f, a2 = 0.f, a3 = 0.f;
        int j = 0;
        for (; j + 4 <= deg; j += 4) {
            int sj0 = __builtin_amdgcn_readlane(srcn, j);
            int sj1 = __builtin_amdgcn_readlane(srcn, j + 1);
            int sj2 = __builtin_amdgcn_readlane(srcn, j + 2);
            int sj3 = __builtin_amdgcn_readlane(srcn, j + 3);
            float w0 = rdlanef(alpha, j);
            float w1 = rdlanef(alpha, j + 1);
            float w2 = rdlanef(alpha, j + 2);
            float w3 = rdlanef(alpha, j + 3);
            a0 = fmaf(w0, xl[(size_t)sj0 * 64 + lane], a0);
            a1 = fmaf(w1, xl[(size_t)sj1 * 64 + lane], a1);
            a2 = fmaf(w2, xl[(size_t)sj2 * 64 + lane], a2);
            a3 = fmaf(w3, xl[(size_t)sj3 * 64 + lane], a3);
        }
        for (; j < deg; ++j) {
            int sj = __builtin_amdgcn_readlane(srcn, j);
            float wj = rdlanef(alpha, j);
            a0 = fmaf(wj, xl[(size_t)sj * 64 + lane], a0);
        }
        acc = (a0 + a1) + (a2 + a3);
    } else {
        // ---- general path (rare): chunked
        float m = NEG_INF;
        for (int b = s; b < e; b += 64) {
            int idx = b + lane;
            float val = (idx < e) ? escr[idx] : NEG_INF;
            #pragma unroll
            for (int off = 32; off; off >>= 1) val = fmaxf(val, __shfl_xor(val, off));
            m = fmaxf(m, val);
        }
        float denom = 0.f;
        for (int b = s; b < e; b += 64) {
            int idx = b + lane;
            float t = (idx < e) ? __expf(escr[idx] - m) : 0.f;
            #pragma unroll
            for (int off = 32; off; off >>= 1) t += __shfl_xor(t, off);
            denom += t;
        }
        float inv = 1.f / (denom + EPS);
        acc = 0.f;
        for (int b = s; b < e; b += 64) {
            int idx = b + lane;
            float wv = (idx < e) ? __expf(escr[idx] - m) * inv : 0.f;
            int srcn = (idx < e) ? ssrc[idx] : 0;
            int nj = min(64, e - b);
            for (int j = 0; j < nj; ++j) {
                float wk = rdlanef(wv, j);
                int sj = __builtin_amdgcn_readlane(srcn, j);
                acc = fmaf(wk, xl[(size_t)sj * 64 + lane], acc);
            }
        }
    }

    float res = fmaxf(acc + bc[lane], 0.f);

    if (MODE == 0) {
        hout[(size_t)v * 64 + lane] = res;
    } else {
        float part = h1[(size_t)v * 64 + lane] * Wout[lane] + res * Wout[64 + lane];
        #pragma unroll
        for (int off = 32; off; off >>= 1) part += __shfl_xor(part, off);
        if (lane == 0) out[v] = part + bout[0];
    }
}

// ================= launch ===================================================

extern "C" void kernel_launch(void* const* d_in, const int* in_sizes, int n_in,
                              void* d_out, int out_size, void* d_ws, size_t ws_size,
                              hipStream_t stream) {
    const float* x     = (const float*)d_in[0];
    const int*   eidx  = (const int*)d_in[1];
    const float* eattr = (const float*)d_in[2];
    const float* Wl1 = (const float*)d_in[4];
    const float* bl1 = (const float*)d_in[5];
    const float* Wr1 = (const float*)d_in[6];
    const float* br1 = (const float*)d_in[7];
    const float* We1 = (const float*)d_in[8];
    const float* att1 = (const float*)d_in[9];
    const float* bc1 = (const float*)d_in[10];
    const float* Wl2 = (const float*)d_in[11];
    const float* bl2 = (const float*)d_in[12];
    const float* Wr2 = (const float*)d_in[13];
    const float* br2 = (const float*)d_in[14];
    const float* We2 = (const float*)d_in[15];
    const float* att2 = (const float*)d_in[16];
    const float* bc2 = (const float*)d_in[17];
    const float* Wout = (const float*)d_in[18];
    const float* bout = (const float*)d_in[19];

    int N = in_sizes[0] / 64;
    int E = in_sizes[1] / 2;
    int M = E + N;
    const int* srcA = eidx;
    const int* dstA = eidx + E;

    char* w = (char*)d_ws;
    size_t used = 0;
    auto alloc = [&](size_t bytes) {
        char* p = w + used;
        used += (bytes + 255) & ~size_t(255);
        return p;
    };
    int*   cnt    = (int*)alloc((size_t)N * 4);
    int*   fill   = (int*)alloc((size_t)N * 4);
    int*   rowptr = (int*)alloc((size_t)(N + 1) * 4);
    int*   bsum   = (int*)alloc(1024 * 4);
    int*   ssrc   = (int*)alloc((size_t)M * 4);
    int*   sdst   = (int*)alloc((size_t)M * 4);
    int*   seid   = (int*)alloc((size_t)M * 4);
    float* escr   = (float*)alloc((size_t)M * 4);
    float* mattr  = (float*)alloc((size_t)N * 16 * 4);
    float* xl     = (float*)alloc((size_t)N * 64 * 4);
    float* xr     = (float*)alloc((size_t)N * 64 * 4);
    float* h1     = (float*)alloc((size_t)N * 64 * 4);
    size_t eperm_bytes = (size_t)M * 16 * 4;
    bool perm = (used + eperm_bytes) <= ws_size;
    float* eperm = perm ? (float*)alloc(eperm_bytes) : nullptr;

    hipMemsetAsync(cnt, 0, (size_t)N * 4, stream);
    hipMemsetAsync(fill, 0, (size_t)N * 4, stream);
    hipMemsetAsync(seid, 0xFF, (size_t)M * 4, stream);

    int NB = (N + 255) / 256;
    count_k<<<(E + 255) / 256, 256, 0, stream>>>(dstA, cnt, E);
    scan1_k<<<NB, 256, 0, stream>>>(cnt, rowptr, bsum, N);
    scan2_k<<<1, 1024, 0, stream>>>(bsum, NB);
    scan3_k<<<NB, 256, 0, stream>>>(rowptr, bsum, N, M);
    fill_k<<<(E + 255) / 256, 256, 0, stream>>>(srcA, dstA, rowptr, fill,
                                                ssrc, sdst, seid, E);

    if (perm) {
        permute_k<<<(M * 4 + 255) / 256, 256, 0, stream>>>(eattr, seid, eperm, M);
        mean_k<1><<<(N * 16 + 255) / 256, 256, 0, stream>>>(
            eattr, seid, rowptr, eperm, mattr, ssrc, sdst, N);
    } else {
        mean_k<0><<<(N * 16 + 255) / 256, 256, 0, stream>>>(
            eattr, seid, rowptr, nullptr, mattr, ssrc, sdst, N);
    }

    int nodeBlocks = (N + 3) / 4;
    int slotBlocks = (M + 511) / 512;   // 512 slots per block (2 per lane)

    // ---- layer 1
    xfrm_k<<<nodeBlocks, 256, 0, stream>>>(x, Wl1, bl1, Wr1, br1, xl, xr, N);
    if (perm)
        escore_k<1><<<slotBlocks, 256, 0, stream>>>(xl, xr, eperm, eattr, seid, mattr,
                                                    ssrc, sdst, We1, att1, escr, M);
    else
        escore_k<0><<<slotBlocks, 256, 0, stream>>>(xl, xr, nullptr, eattr, seid, mattr,
                                                    ssrc, sdst, We1, att1, escr, M);
    aggregate_k<0><<<nodeBlocks, 256, 0, stream>>>(xl, escr, ssrc, rowptr, bc1, h1,
                                                   nullptr, nullptr, nullptr, nullptr, N);

    // ---- layer 2 (+ fused JK-cat readout)
    xfrm_k<<<nodeBlocks, 256, 0, stream>>>(h1, Wl2, bl2, Wr2, br2, xl, xr, N);
    if (perm)
        escore_k<1><<<slotBlocks, 256, 0, stream>>>(xl, xr, eperm, eattr, seid, mattr,
                                                    ssrc, sdst, We2, att2, escr, M);
    else
        escore_k<0><<<slotBlocks, 256, 0, stream>>>(xl, xr, nullptr, eattr, seid, mattr,
                                                    ssrc, sdst, We2, att2, escr, M);
    aggregate_k<1><<<nodeBlocks, 256, 0, stream>>>(xl, escr, ssrc, rowptr, bc2, nullptr,
                                                   h1, Wout, bout, (float*)d_out, N);
}